// Round 4
// baseline (435.969 us; speedup 1.0000x reference)
//
#include <hip/hip_runtime.h>
#include <math.h>

// Problem: B=64, N_total=1029, D=768, r=64, E=4, TOPK=1.
// Fully fused, zero-barrier, deep-prefetch version:
//  - prep_pack (unchanged): weights as bf16 hi/lo MFMA fragments, 1 KB each.
//  - fused: each wave owns 16 tokens end-to-end; NO __syncthreads anywhere.
//    x is prefetched 4 chunks deep in registers (HBM latency cover);
//    weight fragments double-buffered from L2 (one iter ahead).
//
// bf16x3 split: a*b ~= ah*bh + ah*bl + al*bh  (error ~2^-15 rel).
// Fragment map (A and B identical): lane (lg=l>>4,lr=l&15) holds
// M[lr][k0+lg*8+e], e=0..7.  C/D: col=lane&15, row=lg*4+reg [HW-verified].

#define GELU(v) (0.5f*(v)*(1.0f + erff((v)*0.70710678118654752440f)))

typedef __attribute__((ext_vector_type(8))) short bf16x8;
typedef __attribute__((ext_vector_type(4))) float f32x4;

#define MFMA(a,b,c) __builtin_amdgcn_mfma_f32_16x16x32_bf16((a),(b),(c),0,0,0)

__device__ __forceinline__ unsigned pk_hi(float a, float b) {
  return (__float_as_uint(a) >> 16) | (__float_as_uint(b) & 0xFFFF0000u);
}
__device__ __forceinline__ float f_lo(float a) {
  return a - __uint_as_float(__float_as_uint(a) & 0xFFFF0000u);
}
union U8 { unsigned u[4]; bf16x8 v; uint4 q; };
__device__ __forceinline__ bf16x8 hi8(float4 f0, float4 f1) {
  U8 r; r.u[0]=pk_hi(f0.x,f0.y); r.u[1]=pk_hi(f0.z,f0.w);
        r.u[2]=pk_hi(f1.x,f1.y); r.u[3]=pk_hi(f1.z,f1.w); return r.v;
}
__device__ __forceinline__ bf16x8 lo8(float4 f0, float4 f1) {
  U8 r; r.u[0]=pk_hi(f_lo(f0.x),f_lo(f0.y)); r.u[1]=pk_hi(f_lo(f0.z),f_lo(f0.w));
        r.u[2]=pk_hi(f_lo(f1.x),f_lo(f1.y)); r.u[3]=pk_hi(f_lo(f1.z),f_lo(f1.w)); return r.v;
}

// ---------------------------------------------------------------------------
// Fragment layout in wp (fid, 1 KB per fragment; value at (lane,e) =
// Bmat[col = tile*16+lr][k = kc*32 + lg*8 + e]):
//  fid   0..191 : Wd    fid = c*8 + nt*2 + part   (c = kt*2+kc, kt<12, nt<4)
//  fid 192..195 : Wg    fid = 192 + kc*2 + part   (cols 0..3 = experts, pad 0)
//  fid 200..263 : We    fid = 200 + (e*2+kc)*8 + j*2 + part   (j<4)
//  fid 264..455 : Wu    fid = 264 + nt*4 + kc*2 + part        (nt<48)
// ---------------------------------------------------------------------------
__global__ __launch_bounds__(256) void prep_pack(
    const float* __restrict__ Wd, const float* __restrict__ Wg,
    const float* __restrict__ We, const float* __restrict__ Wu,
    char* __restrict__ wp)
{
  int fid = blockIdx.x*4 + (threadIdx.x >> 6);
  if (fid >= 456) return;
  int l = threadIdx.x & 63, lg = l >> 4, lr = l & 15;
  float v[8];
  int part = 0;
  if (fid < 192) {
    int c = fid >> 3, s = fid & 7;
    int kt = c >> 1, kc = c & 1, nt = s >> 1; part = s & 1;
    const float* p = Wd + (size_t)(nt*16 + lr)*768 + kt*64 + kc*32 + lg*8;
    #pragma unroll
    for (int e = 0; e < 8; ++e) v[e] = p[e];
  } else if (fid < 264) {
    int f = fid - 192, ch = f >> 3, s = f & 7;
    if (ch == 0) {
      part = s & 1;
      int kc = (s >> 1) & 1;
      if (s < 4 && lr < 4) {
        const float* p = Wg + lr*64 + kc*32 + lg*8;
        #pragma unroll
        for (int e = 0; e < 8; ++e) v[e] = p[e];
      } else {
        #pragma unroll
        for (int e = 0; e < 8; ++e) v[e] = 0.f;
      }
    } else {
      int e_ = (ch - 1) >> 1, kc = (ch - 1) & 1, j = s >> 1; part = s & 1;
      const float* p = We + (size_t)(e_*64 + j*16 + lr)*64 + kc*32 + lg*8;
      #pragma unroll
      for (int e = 0; e < 8; ++e) v[e] = p[e];
    }
  } else {
    int f = fid - 264;
    int nt = f >> 2, kc = (f >> 1) & 1; part = f & 1;
    const float* p = Wu + (size_t)(nt*16 + lr)*64 + kc*32 + lg*8;
    #pragma unroll
    for (int e = 0; e < 8; ++e) v[e] = p[e];
  }
  U8 rr;
  if (part == 0) {
    rr.u[0]=pk_hi(v[0],v[1]); rr.u[1]=pk_hi(v[2],v[3]);
    rr.u[2]=pk_hi(v[4],v[5]); rr.u[3]=pk_hi(v[6],v[7]);
  } else {
    rr.u[0]=pk_hi(f_lo(v[0]),f_lo(v[1])); rr.u[1]=pk_hi(f_lo(v[2]),f_lo(v[3]));
    rr.u[2]=pk_hi(f_lo(v[4]),f_lo(v[5])); rr.u[3]=pk_hi(f_lo(v[6]),f_lo(v[7]));
  }
  *(uint4*)(wp + (size_t)fid*1024 + (size_t)l*16) = rr.q;
}

// ---------------------------------------------------------------------------
// Fused main kernel. Grid 1029 x 256 (4 waves x 16 tokens). Zero barriers.
// ---------------------------------------------------------------------------
__global__ __launch_bounds__(256, 3) void fused(
    const float* __restrict__ x, const float* __restrict__ be,
    const float* __restrict__ gamma, const char* __restrict__ wp,
    float* __restrict__ out)
{
  __shared__ float sF[4][16][68];      // per-wave private bounce tile
  const int tid = threadIdx.x, bm = blockIdx.x;
  const int wv = tid >> 6, l = tid & 63, lg = l >> 4, lr = l & 15;
  const int tokbase = bm*64 + wv*16 + lg*4;
  const char* wpL = wp + (size_t)l*16;

  // ---- phase 1: t = gelu(x . Wd^T) --------------------------------------
  const float* xrow = x + (size_t)(bm*64 + wv*16 + lr)*768 + lg*8;
  f32x4 t4[4];
  #pragma unroll
  for (int nt = 0; nt < 4; ++nt)
    #pragma unroll
    for (int r = 0; r < 4; ++r) t4[nt][r] = 0.f;

  float4 xqa[4], xqb[4];
  #pragma unroll
  for (int i = 0; i < 4; ++i) {
    xqa[i] = *(const float4*)(xrow + i*32);
    xqb[i] = *(const float4*)(xrow + i*32 + 4);
  }
  bf16x8 Bb[2][8];
  #pragma unroll
  for (int s = 0; s < 8; ++s)
    Bb[0][s] = *(const bf16x8*)(wpL + (size_t)s*1024);

#define P1_STEP(CBASE, I, DO_REFILL, DO_PF) do {                              \
    const int c_ = (CBASE) + (I);                                             \
    if (DO_PF) {                                                              \
      _Pragma("unroll")                                                       \
      for (int s = 0; s < 8; ++s)                                             \
        Bb[((I)+1)&1][s] =                                                    \
            *(const bf16x8*)(wpL + (size_t)((c_+1)*8 + s)*1024);              \
    }                                                                         \
    bf16x8 ah = hi8(xqa[(I)&3], xqb[(I)&3]);                                  \
    bf16x8 al = lo8(xqa[(I)&3], xqb[(I)&3]);                                  \
    if (DO_REFILL) {                                                          \
      xqa[(I)&3] = *(const float4*)(xrow + (c_+4)*32);                        \
      xqb[(I)&3] = *(const float4*)(xrow + (c_+4)*32 + 4);                    \
    }                                                                         \
    _Pragma("unroll")                                                         \
    for (int nt = 0; nt < 4; ++nt) {                                          \
      t4[nt] = MFMA(ah, Bb[(I)&1][nt*2],   t4[nt]);                           \
      t4[nt] = MFMA(ah, Bb[(I)&1][nt*2+1], t4[nt]);                           \
      t4[nt] = MFMA(al, Bb[(I)&1][nt*2],   t4[nt]);                           \
    }                                                                         \
  } while (0)

  for (int cc = 0; cc < 20; cc += 4) {
    P1_STEP(cc, 0, 1, 1);
    P1_STEP(cc, 1, 1, 1);
    P1_STEP(cc, 2, 1, 1);
    P1_STEP(cc, 3, 1, 1);
  }
  P1_STEP(20, 0, 0, 1);
  P1_STEP(20, 1, 0, 1);
  P1_STEP(20, 2, 0, 1);
  P1_STEP(20, 3, 0, 0);
#undef P1_STEP

  // ---- phase 2: gating + experts ----------------------------------------
  // Early issue: be (address-independent) + logit frags + expert step-0 frags.
  float beq[4][4];
  #pragma unroll
  for (int e = 0; e < 4; ++e)
    #pragma unroll
    for (int j = 0; j < 4; ++j)
      beq[e][j] = be[e*64 + j*16 + lr];
  bf16x8 g0h = *(const bf16x8*)(wpL + (size_t)192*1024);
  bf16x8 g0l = *(const bf16x8*)(wpL + (size_t)193*1024);
  bf16x8 g1h = *(const bf16x8*)(wpL + (size_t)194*1024);
  bf16x8 g1l = *(const bf16x8*)(wpL + (size_t)195*1024);
  bf16x8 Eb[2][8];
  #pragma unroll
  for (int s = 0; s < 8; ++s)
    Eb[0][s] = *(const bf16x8*)(wpL + (size_t)(200 + s)*1024);

  // gelu + stash t into wave-private LDS slice, rebuild A-fragments
  #pragma unroll
  for (int nt = 0; nt < 4; ++nt)
    #pragma unroll
    for (int r = 0; r < 4; ++r) {
      float g = GELU(t4[nt][r]);
      t4[nt][r] = g;
      sF[wv][lg*4 + r][nt*16 + lr] = g;
    }
  bf16x8 pah[2], pal[2];
  #pragma unroll
  for (int kc = 0; kc < 2; ++kc) {
    const float* ap = &sF[wv][lr][kc*32 + lg*8];
    float4 a0 = *(const float4*)ap, a1 = *(const float4*)(ap + 4);
    pah[kc] = hi8(a0, a1); pal[kc] = lo8(a0, a1);
  }

  f32x4 lac;
  #pragma unroll
  for (int r = 0; r < 4; ++r) lac[r] = 0.f;
  lac = MFMA(pah[0], g0h, lac); lac = MFMA(pah[0], g0l, lac); lac = MFMA(pal[0], g0h, lac);
  lac = MFMA(pah[1], g1h, lac); lac = MFMA(pah[1], g1l, lac); lac = MFMA(pal[1], g1h, lac);

  float w_[4]; int ei_[4];
  #pragma unroll
  for (int r = 0; r < 4; ++r) {
    float lt = lac[r];
    int base = l & 48;
    float l0 = __shfl(lt, base + 0), l1 = __shfl(lt, base + 1);
    float l2 = __shfl(lt, base + 2), l3 = __shfl(lt, base + 3);
    int ei = 0; float lm = l0;
    if (l1 > lm) { lm = l1; ei = 1; }
    if (l2 > lm) { lm = l2; ei = 2; }
    if (l3 > lm) { lm = l3; ei = 3; }
    float s = expf(l0 - lm) + expf(l1 - lm) + expf(l2 - lm) + expf(l3 - lm);
    float w = 1.0f / s;
    int pos = (tokbase + r) % 1029;     // first 5 tokens of each row: no MoE
    if (pos < 5) w = 0.0f;
    w_[r] = w; ei_[r] = ei;
  }

  f32x4 de[4], sel[4];
  #pragma unroll
  for (int j = 0; j < 4; ++j)
    #pragma unroll
    for (int r = 0; r < 4; ++r) { de[j][r] = 0.f; sel[j][r] = 0.f; }

  #pragma unroll
  for (int st = 0; st < 8; ++st) {
    if (st < 7) {
      #pragma unroll
      for (int s = 0; s < 8; ++s)
        Eb[(st+1)&1][s] = *(const bf16x8*)(wpL + (size_t)(200 + (st+1)*8 + s)*1024);
    }
    const int kc = st & 1;
    #pragma unroll
    for (int j = 0; j < 4; ++j) {
      de[j] = MFMA(pah[kc], Eb[st&1][j*2],   de[j]);
      de[j] = MFMA(pah[kc], Eb[st&1][j*2+1], de[j]);
      de[j] = MFMA(pal[kc], Eb[st&1][j*2],   de[j]);
    }
    if (kc == 1) {
      const int e_ = st >> 1;
      #pragma unroll
      for (int j = 0; j < 4; ++j)
        #pragma unroll
        for (int r = 0; r < 4; ++r) {
          sel[j][r] = (ei_[r] == e_) ? de[j][r] : sel[j][r];
          de[j][r] = 0.f;
        }
    }
  }

  // ---- phase 3: out = (full . Wu^T) * gamma -----------------------------
  // full = t + w*(sel + be[ei]) -> wave slice, rebuild A-frags
  #pragma unroll
  for (int r = 0; r < 4; ++r)
    #pragma unroll
    for (int j = 0; j < 4; ++j) {
      float b0 = beq[0][j], b1 = beq[1][j], b2 = beq[2][j], b3 = beq[3][j];
      float bsel = b0;
      bsel = (ei_[r] == 1) ? b1 : bsel;
      bsel = (ei_[r] == 2) ? b2 : bsel;
      bsel = (ei_[r] == 3) ? b3 : bsel;
      float full = t4[j][r] + w_[r] * (sel[j][r] + bsel);
      sF[wv][lg*4 + r][j*16 + lr] = full;
    }
  bf16x8 a3h[2], a3l[2];
  #pragma unroll
  for (int kc = 0; kc < 2; ++kc) {
    const float* ap = &sF[wv][lr][kc*32 + lg*8];
    float4 a0 = *(const float4*)ap, a1 = *(const float4*)(ap + 4);
    a3h[kc] = hi8(a0, a1); a3l[kc] = lo8(a0, a1);
  }

  bf16x8 Wb[2][4];
  float gq[2];
  #pragma unroll
  for (int f = 0; f < 4; ++f)
    Wb[0][f] = *(const bf16x8*)(wpL + (size_t)(264 + f)*1024);
  gq[0] = gamma[lr];

#define P3_STEP(NT, CUR, NXT, DO_PF) do {                                     \
    if (DO_PF) {                                                              \
      _Pragma("unroll")                                                       \
      for (int f = 0; f < 4; ++f)                                             \
        Wb[NXT][f] =                                                          \
            *(const bf16x8*)(wpL + (size_t)(264 + ((NT)+1)*4 + f)*1024);      \
      gq[NXT] = gamma[((NT)+1)*16 + lr];                                      \
    }                                                                         \
    f32x4 o;                                                                  \
    _Pragma("unroll") for (int r = 0; r < 4; ++r) o[r] = 0.f;                 \
    o = MFMA(a3h[0], Wb[CUR][0], o);                                          \
    o = MFMA(a3h[0], Wb[CUR][1], o);                                          \
    o = MFMA(a3l[0], Wb[CUR][0], o);                                          \
    o = MFMA(a3h[1], Wb[CUR][2], o);                                          \
    o = MFMA(a3h[1], Wb[CUR][3], o);                                          \
    o = MFMA(a3l[1], Wb[CUR][2], o);                                          \
    const int col_ = (NT)*16 + lr;                                            \
    const float gv_ = gq[CUR];                                                \
    _Pragma("unroll") for (int r = 0; r < 4; ++r)                             \
      out[(size_t)(tokbase + r)*768 + col_] = o[r]*gv_;                       \
  } while (0)

  for (int q = 0; q < 23; ++q) {
    P3_STEP(2*q,     0, 1, 1);
    P3_STEP(2*q + 1, 1, 0, 1);
  }
  P3_STEP(46, 0, 1, 1);
  P3_STEP(47, 1, 0, 0);
#undef P3_STEP
}

extern "C" void kernel_launch(void* const* d_in, const int* in_sizes, int n_in,
                              void* d_out, int out_size, void* d_ws, size_t ws_size,
                              hipStream_t stream) {
  const float* x     = (const float*)d_in[0];
  const float* Wd    = (const float*)d_in[1];
  const float* Wg    = (const float*)d_in[2];
  const float* We    = (const float*)d_in[3];
  const float* be    = (const float*)d_in[4];
  const float* Wu    = (const float*)d_in[5];
  const float* gamma = (const float*)d_in[6];
  float* out = (float*)d_out;
  char* wp   = (char*)d_ws;    // 456 KB packed weights

  prep_pack<<<114, 256, 0, stream>>>(Wd, Wg, We, Wu, wp);
  fused<<<1029, 256, 0, stream>>>(x, be, gamma, (const char*)wp, out);
}